// Round 1
// baseline (20312.689 us; speedup 1.0000x reference)
//
#include <hip/hip_runtime.h>
#include <hip/hip_bf16.h>
#include <hip/hip_fp16.h>

// Problem constants
#define T_STEPS 8192
#define O_DIM   1024
#define H_DIM   2048
#define G3      6144      // 3*H
#define A_DIM   512
#define NWG     256       // workgroups in scan (1 per CU)
#define SLICE   8         // hidden indices per WG (= waves per WG)
#define RPW     3         // rows per wave (r, z, n gate rows of own idx)

// X buffer rows: row t+1 holds xi[t] as fp16[6144]; hs[t] (fp32[2048]) is
// written into row t after its xi was consumed.
#define XROW_F32   3072

typedef _Float16 v2h __attribute__((ext_vector_type(2)));

__device__ __forceinline__ float dot8(uint4 w, uint4 h, float acc) {
#if defined(__has_builtin) && __has_builtin(__builtin_amdgcn_fdot2)
    acc = __builtin_amdgcn_fdot2(__builtin_bit_cast(v2h, w.x),
                                 __builtin_bit_cast(v2h, h.x), acc, false);
    acc = __builtin_amdgcn_fdot2(__builtin_bit_cast(v2h, w.y),
                                 __builtin_bit_cast(v2h, h.y), acc, false);
    acc = __builtin_amdgcn_fdot2(__builtin_bit_cast(v2h, w.z),
                                 __builtin_bit_cast(v2h, h.z), acc, false);
    acc = __builtin_amdgcn_fdot2(__builtin_bit_cast(v2h, w.w),
                                 __builtin_bit_cast(v2h, h.w), acc, false);
#else
    const __half2* wh = (const __half2*)&w;
    const __half2* hh = (const __half2*)&h;
    #pragma unroll
    for (int q = 0; q < 4; ++q) {
        float2 wf = __half22float2(wh[q]);
        float2 hf = __half22float2(hh[q]);
        acc = fmaf(wf.x, hf.x, acc);
        acc = fmaf(wf.y, hf.y, acc);
    }
#endif
    return acc;
}

// 64-lane sum, VALU-only (DPP). No LDS traffic, short dependency chain.
// Sequence: row_shr 1/2/4/8 (prefix within 16-lane rows), row_bcast15,
// row_bcast31; total lands in lane 63; readlane broadcasts to all lanes.
__device__ __forceinline__ float dpp_sum64(float v) {
    float s = v;
    int x;
    x = __builtin_amdgcn_update_dpp(0, __builtin_bit_cast(int, s), 0x111, 0xF, 0xF, true);
    s += __builtin_bit_cast(float, x);
    x = __builtin_amdgcn_update_dpp(0, __builtin_bit_cast(int, s), 0x112, 0xF, 0xF, true);
    s += __builtin_bit_cast(float, x);
    x = __builtin_amdgcn_update_dpp(0, __builtin_bit_cast(int, s), 0x114, 0xF, 0xF, true);
    s += __builtin_bit_cast(float, x);
    x = __builtin_amdgcn_update_dpp(0, __builtin_bit_cast(int, s), 0x118, 0xF, 0xF, true);
    s += __builtin_bit_cast(float, x);
    x = __builtin_amdgcn_update_dpp(0, __builtin_bit_cast(int, s), 0x142, 0xF, 0xF, true); // row_bcast15
    s += __builtin_bit_cast(float, x);
    x = __builtin_amdgcn_update_dpp(0, __builtin_bit_cast(int, s), 0x143, 0xF, 0xF, true); // row_bcast31
    s += __builtin_bit_cast(float, x);
    return __builtin_bit_cast(float,
        __builtin_amdgcn_readlane(__builtin_bit_cast(int, s), 63));
}

// ---------------------------------------------------------------------------
// fp32 GEMM:  C[M,N] = A[M,K] @ B[N,K]^T + bias[N]
// 128x128 tile, BK=16, 256 threads, 8x8 per thread.
// OUT_HALF=1 stores C as fp16, else fp32. A row stride lda, C row stride ldc.
// ---------------------------------------------------------------------------
template <int OUT_HALF>
__global__ __launch_bounds__(256) void gemm_bt_bias(
    const float* __restrict__ A, int lda,
    const float* __restrict__ B,
    const float* __restrict__ bias,
    void* __restrict__ Cv, int ldc,
    int M, int N, int K)
{
    __shared__ float As[16][128];
    __shared__ float Bs[16][128];

    const int bm = blockIdx.y * 128;
    const int bn = blockIdx.x * 128;
    const int tid = threadIdx.x;
    const int tm = (tid >> 4) * 8;
    const int tn = (tid & 15) * 8;

    float acc[8][8] = {};

    for (int k0 = 0; k0 < K; k0 += 16) {
        #pragma unroll
        for (int u = 0; u < 2; ++u) {
            const int id = u * 256 + tid;
            const int r = id >> 2;
            const int c = (id & 3) << 2;
            float4 v = *(const float4*)(A + (size_t)(bm + r) * lda + k0 + c);
            As[c + 0][r] = v.x; As[c + 1][r] = v.y;
            As[c + 2][r] = v.z; As[c + 3][r] = v.w;
        }
        #pragma unroll
        for (int u = 0; u < 2; ++u) {
            const int id = u * 256 + tid;
            const int r = id >> 2;
            const int c = (id & 3) << 2;
            float4 v = *(const float4*)(B + (size_t)(bn + r) * K + k0 + c);
            Bs[c + 0][r] = v.x; Bs[c + 1][r] = v.y;
            Bs[c + 2][r] = v.z; Bs[c + 3][r] = v.w;
        }
        __syncthreads();

        #pragma unroll
        for (int kk = 0; kk < 16; ++kk) {
            float a[8], b[8];
            #pragma unroll
            for (int i = 0; i < 8; ++i) a[i] = As[kk][tm + i];
            #pragma unroll
            for (int j = 0; j < 8; ++j) b[j] = Bs[kk][tn + j];
            #pragma unroll
            for (int i = 0; i < 8; ++i)
                #pragma unroll
                for (int j = 0; j < 8; ++j)
                    acc[i][j] = fmaf(a[i], b[j], acc[i][j]);
        }
        __syncthreads();
    }

    if (OUT_HALF) {
        __half* C = (__half*)Cv;
        #pragma unroll
        for (int i = 0; i < 8; ++i) {
            const size_t row = (size_t)(bm + tm + i) * ldc;
            __half tmp[8];
            #pragma unroll
            for (int j = 0; j < 8; ++j)
                tmp[j] = __float2half(acc[i][j] + bias[bn + tn + j]);
            *(uint4*)(C + row + bn + tn) = *(const uint4*)tmp;
        }
    } else {
        float* C = (float*)Cv;
        #pragma unroll
        for (int i = 0; i < 8; ++i) {
            const size_t row = (size_t)(bm + tm + i) * ldc;
            #pragma unroll
            for (int j0 = 0; j0 < 8; j0 += 4) {
                const int n = bn + tn + j0;
                float4 v;
                v.x = acc[i][j0 + 0] + bias[n + 0];
                v.y = acc[i][j0 + 1] + bias[n + 1];
                v.z = acc[i][j0 + 2] + bias[n + 2];
                v.w = acc[i][j0 + 3] + bias[n + 3];
                *(float4*)(C + row + n) = v;
            }
        }
    }
}

// ---------------------------------------------------------------------------
// Persistent cooperative GRU scan, v6: weights in VGPRs + DPP reduce.
// 256 WGs x 512 threads (8 waves). Wave w of WG g owns hidden idx i=8g+w.
// Change vs v5: W_hh slice lives in 48 VGPRs/lane (fp16) instead of LDS,
// and the 64-lane reduce is DPP-only (no ds_swizzle/bpermute). This removes
// ~2000 cycles/step of per-CU LDS-port occupancy (96KB weight reads + 144
// DS shuffle ops per CU per step), which sat on the globally-serialized
// critical path. LDS now holds only h ping-pong (8 KiB).
// Safety invariants (unchanged from v5):
//  - A packet in buf b can only be overwritten with tag t+2 after ALL WGs
//    stored tag t+1, which happens after their poll of tag t on buf b ->
//    no consumer can read a too-new value.
//  - h_lds[t&1] is re-written only at step t+2, which is after barrier(t+1),
//    which certifies all waves finished matvec(t) reads.
// ---------------------------------------------------------------------------
__global__ __launch_bounds__(512, 2) void gru_scan(
    const __half*  __restrict__ xiX,     // X as fp16 rows (stride 6144)
    float*         __restrict__ hsX,     // X as fp32 rows (stride 3072)
    const float*   __restrict__ W_hh,    // [6144, 2048]
    const float*   __restrict__ b_hh,    // [6144]
    unsigned*      __restrict__ pairs)   // [2][2048] packets, pre-zeroed
{
    const int g    = blockIdx.x;
    const int tid  = threadIdx.x;
    const int wave = tid >> 6;
    const int lane = tid & 63;
    const int my_i = g * SLICE + wave;   // hidden index owned by this wave

    __shared__ __align__(16) __half h_lds[2][H_DIM];       // 8 KiB

    // ---- preload own 3 W_hh rows -> fp16 VGPRs (48 regs/lane) -------------
    // wreg[r][j] holds elements [j*512 + lane*8, +8) of row r*H + my_i,
    // matching the h fragment layout hv[j] below.
    uint4 wreg[RPW][4];
    #pragma unroll
    for (int r = 0; r < RPW; ++r) {
        const float* rowp = W_hh + (size_t)(r * H_DIM + my_i) * H_DIM;
        #pragma unroll
        for (int j = 0; j < 4; ++j) {
            const float* src = rowp + j * 512 + lane * 8;
            float4 a = *(const float4*)(src);
            float4 b = *(const float4*)(src + 4);
            __half tmp[8] = { __float2half(a.x), __float2half(a.y),
                              __float2half(a.z), __float2half(a.w),
                              __float2half(b.x), __float2half(b.y),
                              __float2half(b.z), __float2half(b.w) };
            wreg[r][j] = *(const uint4*)tmp;
        }
    }
    float bh_r = 0.f, bh_z = 0.f, bh_n = 0.f;
    if (lane == 0) {
        bh_r = b_hh[my_i];
        bh_z = b_hh[H_DIM + my_i];
        bh_n = b_hh[2 * H_DIM + my_i];
    }

    float h_own = 0.f;   // lane0: fp32 hidden value of own index

    for (int t = 0; t < T_STEPS; ++t) {
        // lane0: prefetch xi for this step (row t+1 of X), plain cached loads
        float xr = 0.f, xz = 0.f, xn = 0.f;
        if (lane == 0) {
            const __half* xp = xiX + (size_t)(t + 1) * G3 + my_i;
            xr = __half2float(xp[0]);
            xz = __half2float(xp[H_DIM]);
            xn = __half2float(xp[2 * H_DIM]);
        }

        // poll own chunk of 256 packets (4/lane), stage bits into h_lds[t&1]
        {
            const unsigned long long* pp = (const unsigned long long*)
                (pairs + (size_t)(t & 1) * H_DIM + wave * 256 + lane * 4);
            const unsigned tgt = (unsigned)t;
            unsigned long long p0, p1;
            for (;;) {
                p0 = __hip_atomic_load(pp + 0, __ATOMIC_RELAXED,
                                       __HIP_MEMORY_SCOPE_AGENT);
                p1 = __hip_atomic_load(pp + 1, __ATOMIC_RELAXED,
                                       __HIP_MEMORY_SCOPE_AGENT);
                bool ok = (((unsigned)(p0 >> 16) & 0xFFFFu) >= tgt) &&
                          (((unsigned)(p0 >> 48))           >= tgt) &&
                          (((unsigned)(p1 >> 16) & 0xFFFFu) >= tgt) &&
                          (((unsigned)(p1 >> 48))           >= tgt);
                if (__all(ok)) break;
                __builtin_amdgcn_s_sleep(1);
            }
            const unsigned long long hbits =
                  (p0 & 0xFFFFull)
                | ((p0 >> 32) & 0xFFFFull) << 16
                | ((p1 & 0xFFFFull) << 32)
                | ((p1 >> 32) & 0xFFFFull) << 48;
            *(unsigned long long*)(&h_lds[t & 1][wave * 256 + lane * 4]) = hbits;
        }
        __syncthreads();   // h_lds[t&1] ready

        // matvec: 3 rows x 2048 via fp16 dot2, fp32 accumulate
        uint4 hv[4];
        #pragma unroll
        for (int j = 0; j < 4; ++j)
            hv[j] = *(const uint4*)(&h_lds[t & 1][j * 512 + lane * 8]);

        float acc[RPW] = {0.f, 0.f, 0.f};
        #pragma unroll
        for (int r = 0; r < RPW; ++r)
            #pragma unroll
            for (int j = 0; j < 4; ++j)
                acc[r] = dot8(wreg[r][j], hv[j], acc[r]);

        // 64-lane sum per row, DPP-only (no LDS port usage)
        #pragma unroll
        for (int r = 0; r < RPW; ++r)
            acc[r] = dpp_sum64(acc[r]);

        // lane0: gates + publish
        if (lane == 0) {
            const float ghr = acc[0] + bh_r;
            const float ghz = acc[1] + bh_z;
            const float ghn = acc[2] + bh_n;
            const float rg = 1.f / (1.f + __expf(-(xr + ghr)));
            const float zg = 1.f / (1.f + __expf(-(xz + ghz)));
            float a = xn + rg * ghn;
            a = fminf(fmaxf(a, -15.f), 15.f);
            const float e2 = __expf(-2.f * a);
            const float ng = (1.f - e2) / (1.f + e2);   // tanh(a)
            const float hnew = (1.f - zg) * ng + zg * h_own;
            h_own = hnew;
            const unsigned pr = ((unsigned)(t + 1) << 16) |
                (unsigned)__half_as_ushort(__float2half(hnew));
            __hip_atomic_store(pairs + (size_t)((t + 1) & 1) * H_DIM + my_i, pr,
                               __ATOMIC_RELAXED, __HIP_MEMORY_SCOPE_AGENT);
            hsX[(size_t)t * XROW_F32 + my_i] = hnew;   // read after kernel end
        }
    }
}

// ---------------------------------------------------------------------------
extern "C" void kernel_launch(void* const* d_in, const int* in_sizes, int n_in,
                              void* d_out, int out_size, void* d_ws, size_t ws_size,
                              hipStream_t stream) {
    const float* obs  = (const float*)d_in[0];
    const float* W_ih = (const float*)d_in[1];
    const float* W_hh = (const float*)d_in[2];
    const float* b_ih = (const float*)d_in[3];
    const float* b_hh = (const float*)d_in[4];
    const float* W_o  = (const float*)d_in[5];
    const float* b_o  = (const float*)d_in[6];
    const float* W_d  = (const float*)d_in[7];
    const float* b_d  = (const float*)d_in[8];
    float* out = (float*)d_out;

    // Workspace layout (~100.8 MiB total):
    //   [4096, 20480)   h packets (2 x 2048 x 4 B), pre-zeroed
    //   [65536, ...)    X buffer: (T+1) rows x 12288 B
    char*     ws    = (char*)d_ws;
    unsigned* pairs = (unsigned*)(ws + 4096);
    char*     X     = ws + 65536;
    __half*   xiX   = (__half*)X;   // fp16 rows, stride 6144
    float*    hsX   = (float*)X;    // fp32 rows, stride 3072

    hipMemsetAsync(d_ws, 0, 65536, stream);

    // Phase 1: xi[t] = obs @ W_ih.T + b_ih  -> fp16 into X row t+1
    gemm_bt_bias<1><<<dim3(G3 / 128, T_STEPS / 128), 256, 0, stream>>>(
        obs, O_DIM, W_ih, b_ih, (void*)(xiX + G3), G3, T_STEPS, G3, O_DIM);

    // Phase 2: sequential GRU scan (cooperative, 256 WGs x 512 threads)
    {
        void* args[] = { (void*)&xiX, (void*)&hsX, (void*)&W_hh, (void*)&b_hh,
                         (void*)&pairs };
        hipLaunchCooperativeKernel((const void*)gru_scan,
                                   dim3(NWG), dim3(512), args, 0, stream);
    }

    // Phase 3: output projections (A = hs rows inside X, lda = 3072)
    gemm_bt_bias<0><<<dim3(A_DIM / 128, T_STEPS / 128), 256, 0, stream>>>(
        (const float*)hsX, XROW_F32, W_o, b_o, (void*)out, A_DIM,
        T_STEPS, A_DIM, H_DIM);
    gemm_bt_bias<0><<<dim3(A_DIM / 128, T_STEPS / 128), 256, 0, stream>>>(
        (const float*)hsX, XROW_F32, W_d, b_d,
        (void*)(out + (size_t)T_STEPS * A_DIM), A_DIM,
        T_STEPS, A_DIM, H_DIM);
}

// Round 3
// 20102.438 us; speedup vs baseline: 1.0105x; 1.0105x over previous
//
#include <hip/hip_runtime.h>
#include <hip/hip_bf16.h>
#include <hip/hip_fp16.h>

// Problem constants
#define T_STEPS 8192
#define O_DIM   1024
#define H_DIM   2048
#define G3      6144      // 3*H
#define A_DIM   512
#define NWG     256       // workgroups in scan (1 per CU)
#define SLICE   8         // hidden indices per WG (= waves per WG)
#define RPW     3         // rows per wave (r, z, n gate rows of own idx)

// X buffer rows: row t+1 holds xi[t] as fp16[6144]; hs[t] (fp32[2048]) is
// written into row t after its xi was consumed.
#define XROW_F32   3072

typedef _Float16 v2h __attribute__((ext_vector_type(2)));

__device__ __forceinline__ float dot8(uint4 w, uint4 h, float acc) {
#if defined(__has_builtin) && __has_builtin(__builtin_amdgcn_fdot2)
    acc = __builtin_amdgcn_fdot2(__builtin_bit_cast(v2h, w.x),
                                 __builtin_bit_cast(v2h, h.x), acc, false);
    acc = __builtin_amdgcn_fdot2(__builtin_bit_cast(v2h, w.y),
                                 __builtin_bit_cast(v2h, h.y), acc, false);
    acc = __builtin_amdgcn_fdot2(__builtin_bit_cast(v2h, w.z),
                                 __builtin_bit_cast(v2h, h.z), acc, false);
    acc = __builtin_amdgcn_fdot2(__builtin_bit_cast(v2h, w.w),
                                 __builtin_bit_cast(v2h, h.w), acc, false);
#else
    const __half2* wh = (const __half2*)&w;
    const __half2* hh = (const __half2*)&h;
    #pragma unroll
    for (int q = 0; q < 4; ++q) {
        float2 wf = __half22float2(wh[q]);
        float2 hf = __half22float2(hh[q]);
        acc = fmaf(wf.x, hf.x, acc);
        acc = fmaf(wf.y, hf.y, acc);
    }
#endif
    return acc;
}

// 64-lane sum, VALU-only (DPP). No LDS traffic, short dependency chain.
// Sequence: row_shr 1/2/4/8 (prefix within 16-lane rows), row_bcast15,
// row_bcast31; total lands in lane 63; readlane broadcasts to all lanes.
__device__ __forceinline__ float dpp_sum64(float v) {
    float s = v;
    int x;
    x = __builtin_amdgcn_update_dpp(0, __builtin_bit_cast(int, s), 0x111, 0xF, 0xF, true);
    s += __builtin_bit_cast(float, x);
    x = __builtin_amdgcn_update_dpp(0, __builtin_bit_cast(int, s), 0x112, 0xF, 0xF, true);
    s += __builtin_bit_cast(float, x);
    x = __builtin_amdgcn_update_dpp(0, __builtin_bit_cast(int, s), 0x114, 0xF, 0xF, true);
    s += __builtin_bit_cast(float, x);
    x = __builtin_amdgcn_update_dpp(0, __builtin_bit_cast(int, s), 0x118, 0xF, 0xF, true);
    s += __builtin_bit_cast(float, x);
    x = __builtin_amdgcn_update_dpp(0, __builtin_bit_cast(int, s), 0x142, 0xF, 0xF, true); // row_bcast15
    s += __builtin_bit_cast(float, x);
    x = __builtin_amdgcn_update_dpp(0, __builtin_bit_cast(int, s), 0x143, 0xF, 0xF, true); // row_bcast31
    s += __builtin_bit_cast(float, x);
    return __builtin_bit_cast(float,
        __builtin_amdgcn_readlane(__builtin_bit_cast(int, s), 63));
}

// ---------------------------------------------------------------------------
// fp32 GEMM:  C[M,N] = A[M,K] @ B[N,K]^T + bias[N]
// 128x128 tile, BK=16, 256 threads, 8x8 per thread.
// OUT_HALF=1 stores C as fp16, else fp32. A row stride lda, C row stride ldc.
// ---------------------------------------------------------------------------
template <int OUT_HALF>
__global__ __launch_bounds__(256) void gemm_bt_bias(
    const float* __restrict__ A, int lda,
    const float* __restrict__ B,
    const float* __restrict__ bias,
    void* __restrict__ Cv, int ldc,
    int M, int N, int K)
{
    __shared__ float As[16][128];
    __shared__ float Bs[16][128];

    const int bm = blockIdx.y * 128;
    const int bn = blockIdx.x * 128;
    const int tid = threadIdx.x;
    const int tm = (tid >> 4) * 8;
    const int tn = (tid & 15) * 8;

    float acc[8][8] = {};

    for (int k0 = 0; k0 < K; k0 += 16) {
        #pragma unroll
        for (int u = 0; u < 2; ++u) {
            const int id = u * 256 + tid;
            const int r = id >> 2;
            const int c = (id & 3) << 2;
            float4 v = *(const float4*)(A + (size_t)(bm + r) * lda + k0 + c);
            As[c + 0][r] = v.x; As[c + 1][r] = v.y;
            As[c + 2][r] = v.z; As[c + 3][r] = v.w;
        }
        #pragma unroll
        for (int u = 0; u < 2; ++u) {
            const int id = u * 256 + tid;
            const int r = id >> 2;
            const int c = (id & 3) << 2;
            float4 v = *(const float4*)(B + (size_t)(bn + r) * K + k0 + c);
            Bs[c + 0][r] = v.x; Bs[c + 1][r] = v.y;
            Bs[c + 2][r] = v.z; Bs[c + 3][r] = v.w;
        }
        __syncthreads();

        #pragma unroll
        for (int kk = 0; kk < 16; ++kk) {
            float a[8], b[8];
            #pragma unroll
            for (int i = 0; i < 8; ++i) a[i] = As[kk][tm + i];
            #pragma unroll
            for (int j = 0; j < 8; ++j) b[j] = Bs[kk][tn + j];
            #pragma unroll
            for (int i = 0; i < 8; ++i)
                #pragma unroll
                for (int j = 0; j < 8; ++j)
                    acc[i][j] = fmaf(a[i], b[j], acc[i][j]);
        }
        __syncthreads();
    }

    if (OUT_HALF) {
        __half* C = (__half*)Cv;
        #pragma unroll
        for (int i = 0; i < 8; ++i) {
            const size_t row = (size_t)(bm + tm + i) * ldc;
            __half tmp[8];
            #pragma unroll
            for (int j = 0; j < 8; ++j)
                tmp[j] = __float2half(acc[i][j] + bias[bn + tn + j]);
            *(uint4*)(C + row + bn + tn) = *(const uint4*)tmp;
        }
    } else {
        float* C = (float*)Cv;
        #pragma unroll
        for (int i = 0; i < 8; ++i) {
            const size_t row = (size_t)(bm + tm + i) * ldc;
            #pragma unroll
            for (int j0 = 0; j0 < 8; j0 += 4) {
                const int n = bn + tn + j0;
                float4 v;
                v.x = acc[i][j0 + 0] + bias[n + 0];
                v.y = acc[i][j0 + 1] + bias[n + 1];
                v.z = acc[i][j0 + 2] + bias[n + 2];
                v.w = acc[i][j0 + 3] + bias[n + 3];
                *(float4*)(C + row + n) = v;
            }
        }
    }
}

// ---------------------------------------------------------------------------
// Persistent cooperative GRU scan, v8: VGPR weights (scalar-pinned) + DPP.
// 256 WGs x 512 threads (8 waves). Wave w of WG g owns hidden idx i=8g+w.
// History: v6 put weights in VGPRs but the compiler rematerialized the
// loads per-step (VGPR_Count=60, +82MB FETCH, +2.5ms). v7 pinned with
// twelve 128-bit "+v" tied asm operands -> miscompiled (absmax 1.15):
// multi-register tied asm operands are unreliable. v8 pins each 32-bit
// component individually ("+v" on uint4 members) — the safe scalar form.
// Safety invariants (unchanged from v5):
//  - A packet in buf b can only be overwritten with tag t+2 after ALL WGs
//    stored tag t+1, which happens after their poll of tag t on buf b ->
//    no consumer can read a too-new value.
//  - h_lds[t&1] is re-written only at step t+2, which is after barrier(t+1),
//    which certifies all waves finished matvec(t) reads.
// ---------------------------------------------------------------------------
__global__ __launch_bounds__(512, 2) void gru_scan(
    const __half*  __restrict__ xiX,     // X as fp16 rows (stride 6144)
    float*         __restrict__ hsX,     // X as fp32 rows (stride 3072)
    const float*   __restrict__ W_hh,    // [6144, 2048]
    const float*   __restrict__ b_hh,    // [6144]
    unsigned*      __restrict__ pairs)   // [2][2048] packets, pre-zeroed
{
    const int g    = blockIdx.x;
    const int tid  = threadIdx.x;
    const int wave = tid >> 6;
    const int lane = tid & 63;
    const int my_i = g * SLICE + wave;   // hidden index owned by this wave

    __shared__ __align__(16) __half h_lds[2][H_DIM];       // 8 KiB

    // ---- preload own 3 W_hh rows -> fp16 VGPRs (48 regs/lane) -------------
    // wreg[r][j] holds elements [j*512 + lane*8, +8) of row r*H + my_i,
    // matching the h fragment layout hv[j] below.
    uint4 wreg[RPW][4];
    #pragma unroll
    for (int r = 0; r < RPW; ++r) {
        const float* rowp = W_hh + (size_t)(r * H_DIM + my_i) * H_DIM;
        #pragma unroll
        for (int j = 0; j < 4; ++j) {
            const float* src = rowp + j * 512 + lane * 8;
            float4 a = *(const float4*)(src);
            float4 b = *(const float4*)(src + 4);
            __align__(16) __half tmp[8] = {
                __float2half(a.x), __float2half(a.y),
                __float2half(a.z), __float2half(a.w),
                __float2half(b.x), __float2half(b.y),
                __float2half(b.z), __float2half(b.w) };
            wreg[r][j] = *(const uint4*)tmp;
        }
    }
    // Pin: redefine every 32-bit component through opaque volatile asm so
    // the register allocator can neither rematerialize the global loads nor
    // sink the fp32->fp16 conversion into the t-loop. Scalar operands only
    // (128-bit tied "+v" operands miscompile — v7 lesson).
    #pragma unroll
    for (int r = 0; r < RPW; ++r)
        asm volatile("" :
            "+v"(wreg[r][0].x), "+v"(wreg[r][0].y),
            "+v"(wreg[r][0].z), "+v"(wreg[r][0].w),
            "+v"(wreg[r][1].x), "+v"(wreg[r][1].y),
            "+v"(wreg[r][1].z), "+v"(wreg[r][1].w),
            "+v"(wreg[r][2].x), "+v"(wreg[r][2].y),
            "+v"(wreg[r][2].z), "+v"(wreg[r][2].w),
            "+v"(wreg[r][3].x), "+v"(wreg[r][3].y),
            "+v"(wreg[r][3].z), "+v"(wreg[r][3].w));

    float bh_r = 0.f, bh_z = 0.f, bh_n = 0.f;
    if (lane == 0) {
        bh_r = b_hh[my_i];
        bh_z = b_hh[H_DIM + my_i];
        bh_n = b_hh[2 * H_DIM + my_i];
    }

    float h_own = 0.f;   // lane0: fp32 hidden value of own index

    for (int t = 0; t < T_STEPS; ++t) {
        // lane0: prefetch xi for this step (row t+1 of X), plain cached loads
        float xr = 0.f, xz = 0.f, xn = 0.f;
        if (lane == 0) {
            const __half* xp = xiX + (size_t)(t + 1) * G3 + my_i;
            xr = __half2float(xp[0]);
            xz = __half2float(xp[H_DIM]);
            xn = __half2float(xp[2 * H_DIM]);
        }

        // poll own chunk of 256 packets (4/lane), stage bits into h_lds[t&1]
        {
            const unsigned long long* pp = (const unsigned long long*)
                (pairs + (size_t)(t & 1) * H_DIM + wave * 256 + lane * 4);
            const unsigned tgt = (unsigned)t;
            unsigned long long p0, p1;
            for (;;) {
                p0 = __hip_atomic_load(pp + 0, __ATOMIC_RELAXED,
                                       __HIP_MEMORY_SCOPE_AGENT);
                p1 = __hip_atomic_load(pp + 1, __ATOMIC_RELAXED,
                                       __HIP_MEMORY_SCOPE_AGENT);
                bool ok = (((unsigned)(p0 >> 16) & 0xFFFFu) >= tgt) &&
                          (((unsigned)(p0 >> 48))           >= tgt) &&
                          (((unsigned)(p1 >> 16) & 0xFFFFu) >= tgt) &&
                          (((unsigned)(p1 >> 48))           >= tgt);
                if (__all(ok)) break;
                __builtin_amdgcn_s_sleep(1);
            }
            const unsigned long long hbits =
                  (p0 & 0xFFFFull)
                | ((p0 >> 32) & 0xFFFFull) << 16
                | ((p1 & 0xFFFFull) << 32)
                | ((p1 >> 32) & 0xFFFFull) << 48;
            *(unsigned long long*)(&h_lds[t & 1][wave * 256 + lane * 4]) = hbits;
        }
        __syncthreads();   // h_lds[t&1] ready

        // matvec: 3 rows x 2048 via fp16 dot2, fp32 accumulate
        uint4 hv[4];
        #pragma unroll
        for (int j = 0; j < 4; ++j)
            hv[j] = *(const uint4*)(&h_lds[t & 1][j * 512 + lane * 8]);

        float acc[RPW] = {0.f, 0.f, 0.f};
        #pragma unroll
        for (int r = 0; r < RPW; ++r)
            #pragma unroll
            for (int j = 0; j < 4; ++j)
                acc[r] = dot8(wreg[r][j], hv[j], acc[r]);

        // 64-lane sum per row, DPP-only (no LDS port usage)
        #pragma unroll
        for (int r = 0; r < RPW; ++r)
            acc[r] = dpp_sum64(acc[r]);

        // lane0: gates + publish
        if (lane == 0) {
            const float ghr = acc[0] + bh_r;
            const float ghz = acc[1] + bh_z;
            const float ghn = acc[2] + bh_n;
            const float rg = 1.f / (1.f + __expf(-(xr + ghr)));
            const float zg = 1.f / (1.f + __expf(-(xz + ghz)));
            float a = xn + rg * ghn;
            a = fminf(fmaxf(a, -15.f), 15.f);
            const float e2 = __expf(-2.f * a);
            const float ng = (1.f - e2) / (1.f + e2);   // tanh(a)
            const float hnew = (1.f - zg) * ng + zg * h_own;
            h_own = hnew;
            const unsigned pr = ((unsigned)(t + 1) << 16) |
                (unsigned)__half_as_ushort(__float2half(hnew));
            __hip_atomic_store(pairs + (size_t)((t + 1) & 1) * H_DIM + my_i, pr,
                               __ATOMIC_RELAXED, __HIP_MEMORY_SCOPE_AGENT);
            hsX[(size_t)t * XROW_F32 + my_i] = hnew;   // read after kernel end
        }
    }
}

// ---------------------------------------------------------------------------
extern "C" void kernel_launch(void* const* d_in, const int* in_sizes, int n_in,
                              void* d_out, int out_size, void* d_ws, size_t ws_size,
                              hipStream_t stream) {
    const float* obs  = (const float*)d_in[0];
    const float* W_ih = (const float*)d_in[1];
    const float* W_hh = (const float*)d_in[2];
    const float* b_ih = (const float*)d_in[3];
    const float* b_hh = (const float*)d_in[4];
    const float* W_o  = (const float*)d_in[5];
    const float* b_o  = (const float*)d_in[6];
    const float* W_d  = (const float*)d_in[7];
    const float* b_d  = (const float*)d_in[8];
    float* out = (float*)d_out;

    // Workspace layout (~100.8 MiB total):
    //   [4096, 20480)   h packets (2 x 2048 x 4 B), pre-zeroed
    //   [65536, ...)    X buffer: (T+1) rows x 12288 B
    char*     ws    = (char*)d_ws;
    unsigned* pairs = (unsigned*)(ws + 4096);
    char*     X     = ws + 65536;
    __half*   xiX   = (__half*)X;   // fp16 rows, stride 6144
    float*    hsX   = (float*)X;    // fp32 rows, stride 3072

    hipMemsetAsync(d_ws, 0, 65536, stream);

    // Phase 1: xi[t] = obs @ W_ih.T + b_ih  -> fp16 into X row t+1
    gemm_bt_bias<1><<<dim3(G3 / 128, T_STEPS / 128), 256, 0, stream>>>(
        obs, O_DIM, W_ih, b_ih, (void*)(xiX + G3), G3, T_STEPS, G3, O_DIM);

    // Phase 2: sequential GRU scan (cooperative, 256 WGs x 512 threads)
    {
        void* args[] = { (void*)&xiX, (void*)&hsX, (void*)&W_hh, (void*)&b_hh,
                         (void*)&pairs };
        hipLaunchCooperativeKernel((const void*)gru_scan,
                                   dim3(NWG), dim3(512), args, 0, stream);
    }

    // Phase 3: output projections (A = hs rows inside X, lda = 3072)
    gemm_bt_bias<0><<<dim3(A_DIM / 128, T_STEPS / 128), 256, 0, stream>>>(
        (const float*)hsX, XROW_F32, W_o, b_o, (void*)out, A_DIM,
        T_STEPS, A_DIM, H_DIM);
    gemm_bt_bias<0><<<dim3(A_DIM / 128, T_STEPS / 128), 256, 0, stream>>>(
        (const float*)hsX, XROW_F32, W_d, b_d,
        (void*)(out + (size_t)T_STEPS * A_DIM), A_DIM,
        T_STEPS, A_DIM, H_DIM);
}

// Round 4
// 17388.986 us; speedup vs baseline: 1.1681x; 1.1560x over previous
//
#include <hip/hip_runtime.h>
#include <hip/hip_bf16.h>
#include <hip/hip_fp16.h>

// Problem constants
#define T_STEPS 8192
#define O_DIM   1024
#define H_DIM   2048
#define G3      6144      // 3*H
#define A_DIM   512
#define NWG     256       // workgroups in scan (1 per CU)
#define SLICE   8         // hidden indices per WG (= waves per WG)
#define NROWS   24        // 3 * SLICE rows of W_hh per WG
#define RPW     3         // rows per wave (r, z, n gate rows of own idx)

// X buffer rows: row t+1 holds xi[t] as fp16[6144]; hs[t] (fp32[2048]) is
// written into row t after its xi was consumed.
#define XROW_F32   3072

typedef _Float16 v2h __attribute__((ext_vector_type(2)));

__device__ __forceinline__ float dot8(uint4 w, uint4 h, float acc) {
#if defined(__has_builtin) && __has_builtin(__builtin_amdgcn_fdot2)
    acc = __builtin_amdgcn_fdot2(__builtin_bit_cast(v2h, w.x),
                                 __builtin_bit_cast(v2h, h.x), acc, false);
    acc = __builtin_amdgcn_fdot2(__builtin_bit_cast(v2h, w.y),
                                 __builtin_bit_cast(v2h, h.y), acc, false);
    acc = __builtin_amdgcn_fdot2(__builtin_bit_cast(v2h, w.z),
                                 __builtin_bit_cast(v2h, h.z), acc, false);
    acc = __builtin_amdgcn_fdot2(__builtin_bit_cast(v2h, w.w),
                                 __builtin_bit_cast(v2h, h.w), acc, false);
#else
    const __half2* wh = (const __half2*)&w;
    const __half2* hh = (const __half2*)&h;
    #pragma unroll
    for (int q = 0; q < 4; ++q) {
        float2 wf = __half22float2(wh[q]);
        float2 hf = __half22float2(hh[q]);
        acc = fmaf(wf.x, hf.x, acc);
        acc = fmaf(wf.y, hf.y, acc);
    }
#endif
    return acc;
}

// 64-lane sum, VALU-only (DPP). No LDS-port usage, short dependency chain.
// Validated numerically in v8 (passed absmax 0.0078).
// Sequence: row_shr 1/2/4/8 (prefix within 16-lane rows), row_bcast15,
// row_bcast31; total lands in lane 63; readlane broadcasts to all lanes.
__device__ __forceinline__ float dpp_sum64(float v) {
    float s = v;
    int x;
    x = __builtin_amdgcn_update_dpp(0, __builtin_bit_cast(int, s), 0x111, 0xF, 0xF, true);
    s += __builtin_bit_cast(float, x);
    x = __builtin_amdgcn_update_dpp(0, __builtin_bit_cast(int, s), 0x112, 0xF, 0xF, true);
    s += __builtin_bit_cast(float, x);
    x = __builtin_amdgcn_update_dpp(0, __builtin_bit_cast(int, s), 0x114, 0xF, 0xF, true);
    s += __builtin_bit_cast(float, x);
    x = __builtin_amdgcn_update_dpp(0, __builtin_bit_cast(int, s), 0x118, 0xF, 0xF, true);
    s += __builtin_bit_cast(float, x);
    x = __builtin_amdgcn_update_dpp(0, __builtin_bit_cast(int, s), 0x142, 0xF, 0xF, true); // row_bcast15
    s += __builtin_bit_cast(float, x);
    x = __builtin_amdgcn_update_dpp(0, __builtin_bit_cast(int, s), 0x143, 0xF, 0xF, true); // row_bcast31
    s += __builtin_bit_cast(float, x);
    return __builtin_bit_cast(float,
        __builtin_amdgcn_readlane(__builtin_bit_cast(int, s), 63));
}

// ---------------------------------------------------------------------------
// fp32 GEMM:  C[M,N] = A[M,K] @ B[N,K]^T + bias[N]
// 128x128 tile, BK=16, 256 threads, 8x8 per thread.
// OUT_HALF=1 stores C as fp16, else fp32. A row stride lda, C row stride ldc.
// ---------------------------------------------------------------------------
template <int OUT_HALF>
__global__ __launch_bounds__(256) void gemm_bt_bias(
    const float* __restrict__ A, int lda,
    const float* __restrict__ B,
    const float* __restrict__ bias,
    void* __restrict__ Cv, int ldc,
    int M, int N, int K)
{
    __shared__ float As[16][128];
    __shared__ float Bs[16][128];

    const int bm = blockIdx.y * 128;
    const int bn = blockIdx.x * 128;
    const int tid = threadIdx.x;
    const int tm = (tid >> 4) * 8;
    const int tn = (tid & 15) * 8;

    float acc[8][8] = {};

    for (int k0 = 0; k0 < K; k0 += 16) {
        #pragma unroll
        for (int u = 0; u < 2; ++u) {
            const int id = u * 256 + tid;
            const int r = id >> 2;
            const int c = (id & 3) << 2;
            float4 v = *(const float4*)(A + (size_t)(bm + r) * lda + k0 + c);
            As[c + 0][r] = v.x; As[c + 1][r] = v.y;
            As[c + 2][r] = v.z; As[c + 3][r] = v.w;
        }
        #pragma unroll
        for (int u = 0; u < 2; ++u) {
            const int id = u * 256 + tid;
            const int r = id >> 2;
            const int c = (id & 3) << 2;
            float4 v = *(const float4*)(B + (size_t)(bn + r) * K + k0 + c);
            Bs[c + 0][r] = v.x; Bs[c + 1][r] = v.y;
            Bs[c + 2][r] = v.z; Bs[c + 3][r] = v.w;
        }
        __syncthreads();

        #pragma unroll
        for (int kk = 0; kk < 16; ++kk) {
            float a[8], b[8];
            #pragma unroll
            for (int i = 0; i < 8; ++i) a[i] = As[kk][tm + i];
            #pragma unroll
            for (int j = 0; j < 8; ++j) b[j] = Bs[kk][tn + j];
            #pragma unroll
            for (int i = 0; i < 8; ++i)
                #pragma unroll
                for (int j = 0; j < 8; ++j)
                    acc[i][j] = fmaf(a[i], b[j], acc[i][j]);
        }
        __syncthreads();
    }

    if (OUT_HALF) {
        __half* C = (__half*)Cv;
        #pragma unroll
        for (int i = 0; i < 8; ++i) {
            const size_t row = (size_t)(bm + tm + i) * ldc;
            __half tmp[8];
            #pragma unroll
            for (int j = 0; j < 8; ++j)
                tmp[j] = __float2half(acc[i][j] + bias[bn + tn + j]);
            *(uint4*)(C + row + bn + tn) = *(const uint4*)tmp;
        }
    } else {
        float* C = (float*)Cv;
        #pragma unroll
        for (int i = 0; i < 8; ++i) {
            const size_t row = (size_t)(bm + tm + i) * ldc;
            #pragma unroll
            for (int j0 = 0; j0 < 8; j0 += 4) {
                const int n = bn + tn + j0;
                float4 v;
                v.x = acc[i][j0 + 0] + bias[n + 0];
                v.y = acc[i][j0 + 1] + bias[n + 1];
                v.z = acc[i][j0 + 2] + bias[n + 2];
                v.w = acc[i][j0 + 3] + bias[n + 3];
                *(float4*)(C + row + n) = v;
            }
        }
    }
}

// ---------------------------------------------------------------------------
// Persistent cooperative GRU scan, v9 = v5 structure + DPP reduce.
// 256 WGs x 512 threads (8 waves). Wave w of WG g owns hidden idx i=8g+w,
// i.e. W_hh rows {w, 8+w, 16+w} (fp16, LDS-resident, 96 KiB).
// History: v6/v8 tried VGPR-resident weights; the allocator spills 48
// loop-invariant VGPRs across the poll loop regardless of asm pins
// (VGPR_Count 60/44, +56-82MB FETCH, +2.2-2.5ms). LDS weights issued
// BEFORE the poll are latency-hidden and stay off the critical path.
// Change vs v5: the post-barrier 64-lane reduce is DPP-only (validated in
// v8) instead of __shfl_xor/ds_bpermute — removes ~850 cycles of contended
// LDS-port occupancy + ~150 cycles of dep latency from the barrier->store
// critical path each step.
// Safety invariants (unchanged from v5):
//  - A packet in buf b can only be overwritten with tag t+2 after ALL WGs
//    stored tag t+1, which happens after their poll of tag t on buf b ->
//    no consumer can read a too-new value.
//  - h_lds[t&1] is re-written only at step t+2, which is after barrier(t+1),
//    which certifies all waves finished matvec(t) reads.
// ---------------------------------------------------------------------------
__global__ __launch_bounds__(512) void gru_scan(
    const __half*  __restrict__ xiX,     // X as fp16 rows (stride 6144)
    float*         __restrict__ hsX,     // X as fp32 rows (stride 3072)
    const float*   __restrict__ W_hh,    // [6144, 2048]
    const float*   __restrict__ b_hh,    // [6144]
    unsigned*      __restrict__ pairs)   // [2][2048] packets, pre-zeroed
{
    const int g    = blockIdx.x;
    const int tid  = threadIdx.x;
    const int wave = tid >> 6;
    const int lane = tid & 63;
    const int my_i = g * SLICE + wave;   // hidden index owned by this wave

    __shared__ __align__(16) __half w_lds[NROWS][H_DIM];   // 96 KiB
    __shared__ __align__(16) __half h_lds[2][H_DIM];       // 8 KiB

    // ---- preload W_hh slice -> fp16 LDS (coalesced float4 loads) ----------
    for (int l = 0; l < NROWS; ++l) {
        const int grow = (l >> 3) * H_DIM + g * SLICE + (l & 7);
        float4 v = *(const float4*)(W_hh + (size_t)grow * H_DIM + tid * 4);
        __half tmp[4] = { __float2half(v.x), __float2half(v.y),
                          __float2half(v.z), __float2half(v.w) };
        *(uint2*)(&w_lds[l][tid * 4]) = *(const uint2*)tmp;
    }
    float bh_r = 0.f, bh_z = 0.f, bh_n = 0.f;
    if (lane == 0) {
        bh_r = b_hh[my_i];
        bh_z = b_hh[H_DIM + my_i];
        bh_n = b_hh[2 * H_DIM + my_i];
    }
    __syncthreads();

    float h_own = 0.f;   // lane0: fp32 hidden value of own index

    for (int t = 0; t < T_STEPS; ++t) {
        // lane0: prefetch xi for this step (row t+1 of X), plain cached loads
        float xr = 0.f, xz = 0.f, xn = 0.f;
        if (lane == 0) {
            const __half* xp = xiX + (size_t)(t + 1) * G3 + my_i;
            xr = __half2float(xp[0]);
            xz = __half2float(xp[H_DIM]);
            xn = __half2float(xp[2 * H_DIM]);
        }

        // issue weight ds_reads now: LDS port works during the poll wait
        uint4 wv[RPW][4];
        #pragma unroll
        for (int r = 0; r < RPW; ++r)
            #pragma unroll
            for (int j = 0; j < 4; ++j)
                wv[r][j] = *(const uint4*)(&w_lds[r * 8 + wave][j * 512 + lane * 8]);

        // poll own chunk of 256 packets (4/lane), stage bits into h_lds[t&1]
        {
            const unsigned long long* pp = (const unsigned long long*)
                (pairs + (size_t)(t & 1) * H_DIM + wave * 256 + lane * 4);
            const unsigned tgt = (unsigned)t;
            unsigned long long p0, p1;
            for (;;) {
                p0 = __hip_atomic_load(pp + 0, __ATOMIC_RELAXED,
                                       __HIP_MEMORY_SCOPE_AGENT);
                p1 = __hip_atomic_load(pp + 1, __ATOMIC_RELAXED,
                                       __HIP_MEMORY_SCOPE_AGENT);
                bool ok = (((unsigned)(p0 >> 16) & 0xFFFFu) >= tgt) &&
                          (((unsigned)(p0 >> 48))           >= tgt) &&
                          (((unsigned)(p1 >> 16) & 0xFFFFu) >= tgt) &&
                          (((unsigned)(p1 >> 48))           >= tgt);
                if (__all(ok)) break;
                __builtin_amdgcn_s_sleep(1);
            }
            const unsigned long long hbits =
                  (p0 & 0xFFFFull)
                | ((p0 >> 32) & 0xFFFFull) << 16
                | ((p1 & 0xFFFFull) << 32)
                | ((p1 >> 32) & 0xFFFFull) << 48;
            *(unsigned long long*)(&h_lds[t & 1][wave * 256 + lane * 4]) = hbits;
        }
        __syncthreads();   // h_lds[t&1] ready

        // matvec: 3 rows x 2048 via fp16 dot2, fp32 accumulate
        uint4 hv[4];
        #pragma unroll
        for (int j = 0; j < 4; ++j)
            hv[j] = *(const uint4*)(&h_lds[t & 1][j * 512 + lane * 8]);

        float acc[RPW] = {0.f, 0.f, 0.f};
        #pragma unroll
        for (int r = 0; r < RPW; ++r)
            #pragma unroll
            for (int j = 0; j < 4; ++j)
                acc[r] = dot8(wv[r][j], hv[j], acc[r]);

        // 64-lane sum per row, DPP-only (no LDS port, no inter-wave
        // contention on the barrier->store critical path)
        #pragma unroll
        for (int r = 0; r < RPW; ++r)
            acc[r] = dpp_sum64(acc[r]);

        // lane0: gates + publish
        if (lane == 0) {
            const float ghr = acc[0] + bh_r;
            const float ghz = acc[1] + bh_z;
            const float ghn = acc[2] + bh_n;
            const float rg = 1.f / (1.f + __expf(-(xr + ghr)));
            const float zg = 1.f / (1.f + __expf(-(xz + ghz)));
            float a = xn + rg * ghn;
            a = fminf(fmaxf(a, -15.f), 15.f);
            const float e2 = __expf(-2.f * a);
            const float ng = (1.f - e2) / (1.f + e2);   // tanh(a)
            const float hnew = (1.f - zg) * ng + zg * h_own;
            h_own = hnew;
            const unsigned pr = ((unsigned)(t + 1) << 16) |
                (unsigned)__half_as_ushort(__float2half(hnew));
            __hip_atomic_store(pairs + (size_t)((t + 1) & 1) * H_DIM + my_i, pr,
                               __ATOMIC_RELAXED, __HIP_MEMORY_SCOPE_AGENT);
            hsX[(size_t)t * XROW_F32 + my_i] = hnew;   // read after kernel end
        }
    }
}

// ---------------------------------------------------------------------------
extern "C" void kernel_launch(void* const* d_in, const int* in_sizes, int n_in,
                              void* d_out, int out_size, void* d_ws, size_t ws_size,
                              hipStream_t stream) {
    const float* obs  = (const float*)d_in[0];
    const float* W_ih = (const float*)d_in[1];
    const float* W_hh = (const float*)d_in[2];
    const float* b_ih = (const float*)d_in[3];
    const float* b_hh = (const float*)d_in[4];
    const float* W_o  = (const float*)d_in[5];
    const float* b_o  = (const float*)d_in[6];
    const float* W_d  = (const float*)d_in[7];
    const float* b_d  = (const float*)d_in[8];
    float* out = (float*)d_out;

    // Workspace layout (~100.8 MiB total):
    //   [4096, 20480)   h packets (2 x 2048 x 4 B), pre-zeroed
    //   [65536, ...)    X buffer: (T+1) rows x 12288 B
    char*     ws    = (char*)d_ws;
    unsigned* pairs = (unsigned*)(ws + 4096);
    char*     X     = ws + 65536;
    __half*   xiX   = (__half*)X;   // fp16 rows, stride 6144
    float*    hsX   = (float*)X;    // fp32 rows, stride 3072

    hipMemsetAsync(d_ws, 0, 65536, stream);

    // Phase 1: xi[t] = obs @ W_ih.T + b_ih  -> fp16 into X row t+1
    gemm_bt_bias<1><<<dim3(G3 / 128, T_STEPS / 128), 256, 0, stream>>>(
        obs, O_DIM, W_ih, b_ih, (void*)(xiX + G3), G3, T_STEPS, G3, O_DIM);

    // Phase 2: sequential GRU scan (cooperative, 256 WGs x 512 threads)
    {
        void* args[] = { (void*)&xiX, (void*)&hsX, (void*)&W_hh, (void*)&b_hh,
                         (void*)&pairs };
        hipLaunchCooperativeKernel((const void*)gru_scan,
                                   dim3(NWG), dim3(512), args, 0, stream);
    }

    // Phase 3: output projections (A = hs rows inside X, lda = 3072)
    gemm_bt_bias<0><<<dim3(A_DIM / 128, T_STEPS / 128), 256, 0, stream>>>(
        (const float*)hsX, XROW_F32, W_o, b_o, (void*)out, A_DIM,
        T_STEPS, A_DIM, H_DIM);
    gemm_bt_bias<0><<<dim3(A_DIM / 128, T_STEPS / 128), 256, 0, stream>>>(
        (const float*)hsX, XROW_F32, W_d, b_d,
        (void*)(out + (size_t)T_STEPS * A_DIM), A_DIM,
        T_STEPS, A_DIM, H_DIM);
}